// Round 16
// baseline (336.985 us; speedup 1.0000x reference)
//
#include <hip/hip_runtime.h>
#include <hip/hip_bf16.h>
#include <cstdint>
#include <cstddef>

#define S_LEN 2048
#define HID   4096
#define HD    128
#define NH    32
#define NKV   8
#define KVW   (NKV * HD)        /* 1024 */
#define QKVN  (HID + 2 * KVW)   /* 6144 */

typedef __bf16 bf16x8_t __attribute__((ext_vector_type(8)));
typedef float  f32x4_t  __attribute__((ext_vector_type(4)));
typedef unsigned short u16x8_t __attribute__((ext_vector_type(8)));

__device__ __forceinline__ unsigned short f2b(float f) {
  unsigned u = __float_as_uint(f);
  u += 0x7FFFu + ((u >> 16) & 1u);
  return (unsigned short)(u >> 16);
}
__device__ __forceinline__ float b2f(unsigned short v) {
  return __uint_as_float(((unsigned)v) << 16);
}
// raw v_exp_f32: D = 2^S0
__device__ __forceinline__ float fexp2(float x) {
  float r;
  asm("v_exp_f32 %0, %1" : "=v"(r) : "v"(x));
  return r;
}
__device__ __forceinline__ void gld_lds16(const void* g, void* l) {
  __builtin_amdgcn_global_load_lds(
      (const __attribute__((address_space(1))) void*)g,
      (__attribute__((address_space(3))) void*)l, 16, 0, 0);
}

// ---------- fused fp32 -> bf16 conversion: X | Wq | Wk | Wv in ONE launch ----------
__global__ void cvt4_kernel(const float* __restrict__ s0, const float* __restrict__ s1,
                            const float* __restrict__ s2, const float* __restrict__ s3,
                            unsigned short* __restrict__ dst) {
  const int B0 = 2097152;
  const int B1 = B0 + 4194304;
  const int B2 = B1 + 1048576;
  const int B3 = B2 + 1048576;
  int i = blockIdx.x * blockDim.x + threadIdx.x;
  int stride = gridDim.x * blockDim.x;
  for (; i < B3; i += stride) {
    const float* s; int off;
    if (i < B0)      { s = s0; off = i; }
    else if (i < B1) { s = s1; off = i - B0; }
    else if (i < B2) { s = s2; off = i - B1; }
    else             { s = s3; off = i - B2; }
    float4 v = reinterpret_cast<const float4*>(s)[off];
    ushort4 o;
    o.x = f2b(v.x); o.y = f2b(v.y); o.z = f2b(v.z); o.w = f2b(v.w);
    reinterpret_cast<ushort4*>(dst)[i] = o;
  }
}

// ---------------- RoPE (in-place on bf16 Q and K) ----------------
#define QSCALE 0.12751744846f   /* 1/sqrt(128) * log2(e) */
__global__ void rope_kernel(unsigned short* __restrict__ Q,
                            unsigned short* __restrict__ Kb,
                            const int* __restrict__ pos_ids) {
  const int total = S_LEN * (NH + NKV) * 64;
  int idx = blockIdx.x * blockDim.x + threadIdx.x;
  int stride = gridDim.x * blockDim.x;
  for (; idx < total; idx += stride) {
    int s   = idx / ((NH + NKV) * 64);
    int rem = idx % ((NH + NKV) * 64);
    int hp  = rem >> 6;
    int i   = rem & 63;
    unsigned short* ptr; int W, h;
    if (hp < NH) { ptr = Q;  W = HID; h = hp; }
    else         { ptr = Kb; W = KVW; h = hp - NH; }
    float pos = (float)pos_ids[s];
    float ang = pos * __expf(-(float)i * 0.14391156516f);
    float sn, cs;
    sincosf(ang, &sn, &cs);
    size_t base = (size_t)s * W + (size_t)h * HD + i;
    float lo = b2f(ptr[base]);
    float hi = b2f(ptr[base + 64]);
    float o0 = lo * cs - hi * sn;
    float o1 = hi * cs + lo * sn;
    if (hp < NH) { o0 *= QSCALE; o1 *= QSCALE; }
    ptr[base]      = f2b(o0);
    ptr[base + 64] = f2b(o1);
  }
}

// ------------- 8-wave 4-phase pipelined GEMM, 2 blocks/CU (r12, proven) -------------
template <int BN, int MODE>
__global__ __launch_bounds__(512, 4) void gemm4p_kernel(
    const unsigned short* __restrict__ A, const unsigned short* __restrict__ B,
    void* __restrict__ C0, void* __restrict__ C1, void* __restrict__ C2,
    int N, int K) {
  constexpr int NFR = BN / 64;
  constexpr int ABYTES = 128 * 128;
  constexpr int TILE_LDS = ABYTES + BN * 128;
  __shared__ char ldsB[2 * TILE_LDS];

  const int tid  = threadIdx.x;
  const int lane = tid & 63;
  const int wid  = tid >> 6;
  const int wm = wid >> 2, wn = wid & 3;
  const int lr = lane & 15, g = lane >> 4;
  const int bm = blockIdx.y * 128;
  const int bn = blockIdx.x * BN;
  const int nk = K >> 6;
  const int ni = nk >> 1;
  const int xr = (lr & 7) << 4;

  auto stage_u = [&](int t, int u) {
    if (t >= nk) return;
    const int riu = tid >> 3;
    const int cbs = ((tid & 7) << 4) ^ ((riu & 7) << 4);
    const char* src;
    if (u < 2)
      src = (const char*)A + ((size_t)(bm + u * 64 + riu) * K + t * 64) * 2 + cbs;
    else
      src = (const char*)B + ((size_t)(bn + (u - 2) * 64 + riu) * K + t * 64) * 2 + cbs;
    gld_lds16(src, ldsB + (t & 1) * TILE_LDS + u * 8192 + tid * 16);
  };

  auto rdA = [&](const char* bb, int m, int k) {
    const int row = wm * 64 + m * 16 + lr;
    return *(const bf16x8_t*)(bb + row * 128 + ((k * 64 + g * 16) ^ xr));
  };
  auto rdB = [&](const char* bb, int n, int k) {
    const int row = wn * (BN / 4) + n * 16 + lr;
    return *(const bf16x8_t*)(bb + ABYTES + row * 128 + ((k * 64 + g * 16) ^ xr));
  };

  for (int t = 0; t < 2; ++t)
    for (int u = 0; u < 2 + NFR; ++u) stage_u(t, u);
  asm volatile("s_waitcnt vmcnt(0)" ::: "memory");
  __builtin_amdgcn_sched_barrier(0);
  __builtin_amdgcn_s_barrier();

  f32x4_t acc[4][NFR];
#pragma unroll
  for (int m = 0; m < 4; ++m)
#pragma unroll
    for (int n = 0; n < NFR; ++n) acc[m][n] = f32x4_t{0.f, 0.f, 0.f, 0.f};

  bf16x8_t bfr[NFR][2], af[2][2];

#define MFMA_BLOCK(MB)                                                        \
  __builtin_amdgcn_s_setprio(1);                                              \
  _Pragma("unroll") for (int m = 0; m < 2; ++m)                               \
    _Pragma("unroll") for (int n = 0; n < NFR; ++n)                           \
      _Pragma("unroll") for (int k = 0; k < 2; ++k)                           \
        acc[(MB) + m][n] = __builtin_amdgcn_mfma_f32_16x16x32_bf16(           \
            af[m][k], bfr[n][k], acc[(MB) + m][n], 0, 0, 0);                  \
  __builtin_amdgcn_s_setprio(0);

#define GATE()                                                                \
  __builtin_amdgcn_s_barrier();                                               \
  asm volatile("s_waitcnt lgkmcnt(0)" ::: "memory");                          \
  __builtin_amdgcn_sched_barrier(0);

#define RD_A2(bb, m0)                                                         \
  _Pragma("unroll") for (int m = 0; m < 2; ++m)                               \
    _Pragma("unroll") for (int k = 0; k < 2; ++k)                             \
      af[m][k] = rdA(bb, (m0) + m, k);

#define RD_B(bb)                                                              \
  _Pragma("unroll") for (int n = 0; n < NFR; ++n)                             \
    _Pragma("unroll") for (int k = 0; k < 2; ++k)                             \
      bfr[n][k] = rdB(bb, n, k);

  for (int i = 0; i < ni; ++i) {
    const char* bE = ldsB;
    const char* bO = ldsB + TILE_LDS;
    const int tO = 2 * i + 1, tE2 = 2 * i + 2, tO2 = 2 * i + 3;
    const bool last = (i == ni - 1);

    RD_B(bE);
    RD_A2(bE, 0);
    if (i > 0) { stage_u(tO, 0); stage_u(tO, 1); }
    GATE(); MFMA_BLOCK(0);
    __builtin_amdgcn_s_barrier();

    RD_A2(bE, 2);
#pragma unroll
    for (int u = 0; u < NFR; ++u) stage_u(tE2, 2 + u);
    GATE(); MFMA_BLOCK(2);
    if (last) { asm volatile("s_waitcnt vmcnt(0)" ::: "memory"); }
    else      { asm volatile("s_waitcnt vmcnt(%0)" :: "n"(NFR) : "memory"); }
    __builtin_amdgcn_sched_barrier(0);
    __builtin_amdgcn_s_barrier();

    RD_B(bO);
    RD_A2(bO, 0);
    stage_u(tE2, 0); stage_u(tE2, 1);
    GATE(); MFMA_BLOCK(0);
    __builtin_amdgcn_s_barrier();

    RD_A2(bO, 2);
#pragma unroll
    for (int u = 0; u < NFR; ++u) stage_u(tO2, 2 + u);
    GATE(); MFMA_BLOCK(2);
    if (!last) { asm volatile("s_waitcnt vmcnt(%0)" :: "n"(NFR) : "memory"); }
    __builtin_amdgcn_sched_barrier(0);
    __builtin_amdgcn_s_barrier();
  }
#undef MFMA_BLOCK
#undef GATE
#undef RD_A2
#undef RD_B

#pragma unroll
  for (int mf = 0; mf < 4; ++mf) {
    const int row0 = bm + wm * 64 + mf * 16 + g * 4;
#pragma unroll
    for (int nf = 0; nf < NFR; ++nf) {
      const int col = bn + wn * (BN / 4) + nf * 16 + lr;
      if constexpr (MODE == 1) {
#pragma unroll
        for (int r = 0; r < 4; ++r)
          ((float*)C0)[(size_t)(row0 + r) * N + col] = acc[mf][nf][r];
      } else {
        if (col < HID) {
#pragma unroll
          for (int r = 0; r < 4; ++r)
            ((unsigned short*)C0)[(size_t)(row0 + r) * HID + col] = f2b(acc[mf][nf][r]);
        } else if (col < HID + KVW) {
#pragma unroll
          for (int r = 0; r < 4; ++r)
            ((unsigned short*)C1)[(size_t)(row0 + r) * KVW + (col - HID)] = f2b(acc[mf][nf][r]);
        } else {
          const int c2 = col - HID - KVW;
          ushort4 w;
          w.x = f2b(acc[mf][nf][0]); w.y = f2b(acc[mf][nf][1]);
          w.z = f2b(acc[mf][nf][2]); w.w = f2b(acc[mf][nf][3]);
          *(ushort4*)(void*)&((unsigned short*)C2)[(size_t)c2 * S_LEN + row0] = w;
        }
      }
    }
  }
}

// ---- 4-wave 4-phase pipelined GEMM (r13) — short out-proj ----
template <int BN, int MODE>
__global__ __launch_bounds__(256, 2) void gemm4w_kernel(
    const unsigned short* __restrict__ A, const unsigned short* __restrict__ B,
    void* __restrict__ C0, void* __restrict__ C1, void* __restrict__ C2,
    int N, int K) {
  constexpr int NFRW = BN / 32;
  constexpr int ABYTES = 128 * 128;
  constexpr int TILE_LDS = ABYTES + BN * 128;
  __shared__ char ldsB[2 * TILE_LDS];

  const int tid  = threadIdx.x;
  const int lane = tid & 63;
  const int wid  = tid >> 6;
  const int wm = wid >> 1, wn = wid & 1;
  const int lr = lane & 15, g = lane >> 4;
  const int bm = blockIdx.y * 128;
  const int bn = blockIdx.x * BN;
  const int nk = K >> 6;
  const int ni = nk >> 1;
  const int xr = (lr & 7) << 4;

  auto stage_u = [&](int t, int u) {
    if (t >= nk) return;
    const int riu = tid >> 3;
    const int cbs = ((tid & 7) << 4) ^ ((riu & 7) << 4);
    const char* src;
    if (u < 4)
      src = (const char*)A + ((size_t)(bm + u * 32 + riu) * K + t * 64) * 2 + cbs;
    else
      src = (const char*)B + ((size_t)(bn + (u - 4) * 32 + riu) * K + t * 64) * 2 + cbs;
    gld_lds16(src, ldsB + (t & 1) * TILE_LDS + u * 4096 + tid * 16);
  };

  auto rdA = [&](const char* bb, int m, int k) {
    const int row = wm * 64 + m * 16 + lr;
    return *(const bf16x8_t*)(bb + row * 128 + ((k * 64 + g * 16) ^ xr));
  };
  auto rdB = [&](const char* bb, int n, int k) {
    const int row = wn * (BN / 2) + n * 16 + lr;
    return *(const bf16x8_t*)(bb + ABYTES + row * 128 + ((k * 64 + g * 16) ^ xr));
  };

  for (int t = 0; t < 2; ++t)
    for (int u = 0; u < 4 + NFRW; ++u) stage_u(t, u);
  asm volatile("s_waitcnt vmcnt(0)" ::: "memory");
  __builtin_amdgcn_sched_barrier(0);
  __builtin_amdgcn_s_barrier();

  f32x4_t acc[4][NFRW];
#pragma unroll
  for (int m = 0; m < 4; ++m)
#pragma unroll
    for (int n = 0; n < NFRW; ++n) acc[m][n] = f32x4_t{0.f, 0.f, 0.f, 0.f};

  bf16x8_t bfr[NFRW][2], af[2][2];

#define MFMA_BLOCK(MB)                                                        \
  __builtin_amdgcn_s_setprio(1);                                              \
  _Pragma("unroll") for (int m = 0; m < 2; ++m)                               \
    _Pragma("unroll") for (int n = 0; n < NFRW; ++n)                          \
      _Pragma("unroll") for (int k = 0; k < 2; ++k)                           \
        acc[(MB) + m][n] = __builtin_amdgcn_mfma_f32_16x16x32_bf16(           \
            af[m][k], bfr[n][k], acc[(MB) + m][n], 0, 0, 0);                  \
  __builtin_amdgcn_s_setprio(0);

#define GATE()                                                                \
  __builtin_amdgcn_s_barrier();                                               \
  asm volatile("s_waitcnt lgkmcnt(0)" ::: "memory");                          \
  __builtin_amdgcn_sched_barrier(0);

#define RD_A2(bb, m0)                                                         \
  _Pragma("unroll") for (int m = 0; m < 2; ++m)                               \
    _Pragma("unroll") for (int k = 0; k < 2; ++k)                             \
      af[m][k] = rdA(bb, (m0) + m, k);

#define RD_B(bb)                                                              \
  _Pragma("unroll") for (int n = 0; n < NFRW; ++n)                            \
    _Pragma("unroll") for (int k = 0; k < 2; ++k)                             \
      bfr[n][k] = rdB(bb, n, k);

  for (int i = 0; i < ni; ++i) {
    const char* bE = ldsB;
    const char* bO = ldsB + TILE_LDS;
    const int tO = 2 * i + 1, tE2 = 2 * i + 2, tO2 = 2 * i + 3;
    const bool last = (i == ni - 1);

    RD_B(bE);
    RD_A2(bE, 0);
    if (i > 0) {
#pragma unroll
      for (int u = 0; u < 4; ++u) stage_u(tO, u);
    }
    GATE(); MFMA_BLOCK(0);
    __builtin_amdgcn_s_barrier();

    RD_A2(bE, 2);
#pragma unroll
    for (int u = 0; u < NFRW; ++u) stage_u(tE2, 4 + u);
    GATE(); MFMA_BLOCK(2);
    if (last) { asm volatile("s_waitcnt vmcnt(0)" ::: "memory"); }
    else      { asm volatile("s_waitcnt vmcnt(%0)" :: "n"(NFRW) : "memory"); }
    __builtin_amdgcn_sched_barrier(0);
    __builtin_amdgcn_s_barrier();

    RD_B(bO);
    RD_A2(bO, 0);
#pragma unroll
    for (int u = 0; u < 4; ++u) stage_u(tE2, u);
    GATE(); MFMA_BLOCK(0);
    __builtin_amdgcn_s_barrier();

    RD_A2(bO, 2);
#pragma unroll
    for (int u = 0; u < NFRW; ++u) stage_u(tO2, 4 + u);
    GATE(); MFMA_BLOCK(2);
    if (!last) { asm volatile("s_waitcnt vmcnt(%0)" :: "n"(NFRW) : "memory"); }
    __builtin_amdgcn_sched_barrier(0);
    __builtin_amdgcn_s_barrier();
  }
#undef MFMA_BLOCK
#undef GATE
#undef RD_A2
#undef RD_B

#pragma unroll
  for (int mf = 0; mf < 4; ++mf) {
    const int row0 = bm + wm * 64 + mf * 16 + g * 4;
#pragma unroll
    for (int nf = 0; nf < NFRW; ++nf) {
      const int col = bn + wn * (BN / 2) + nf * 16 + lr;
      if constexpr (MODE == 1) {
#pragma unroll
        for (int r = 0; r < 4; ++r)
          ((float*)C0)[(size_t)(row0 + r) * N + col] = acc[mf][nf][r];
      } else {
        if (col < HID) {
#pragma unroll
          for (int r = 0; r < 4; ++r)
            ((unsigned short*)C0)[(size_t)(row0 + r) * HID + col] = f2b(acc[mf][nf][r]);
        } else if (col < HID + KVW) {
#pragma unroll
          for (int r = 0; r < 4; ++r)
            ((unsigned short*)C1)[(size_t)(row0 + r) * KVW + (col - HID)] = f2b(acc[mf][nf][r]);
        } else {
          const int c2 = col - HID - KVW;
          ushort4 w;
          w.x = f2b(acc[mf][nf][0]); w.y = f2b(acc[mf][nf][1]);
          w.z = f2b(acc[mf][nf][2]); w.w = f2b(acc[mf][nf][3]);
          *(ushort4*)(void*)&((unsigned short*)C2)[(size_t)c2 * S_LEN + row0] = w;
        }
      }
    }
  }
}

// -------- flash attention v6: 2q x 2kv wave split + hidden Wo-cvt --------
// r15 showed attn is LDS-BW-bound (each wave read ALL of K/V: 4x amp).
// Wave w: qh=w>>1 owns q rows [qh*32,+32); kh=w&1 owns kv rows [kh*32,+32)
// of each 64-tile -> K/V read amplification 4x -> 2x (16 b128/wave/tile).
// Each wave keeps independent online-softmax (m,l,oacc) over its kv slice;
// per-pass merge across the wave pair via LDS (K buffer reused after the
// final tile barrier): O = (w0*O0 + w1*O1) / (w0*l0 + w1*l1), wi=2^(mi-m*).
// m_init=-1e30 vs mask=-3e38: fully-masked slice gives exp(-3e38+1e30)->0
// (avoids the 0-diff -> exp(0)=1 trap).
__global__ __launch_bounds__(256) void attn_kernel(
    const unsigned short* __restrict__ Q, const unsigned short* __restrict__ K,
    const unsigned short* __restrict__ VtG, unsigned short* __restrict__ O,
    const float* __restrict__ WoF, unsigned short* __restrict__ WoB) {
  __shared__ char KlB[2][16384];
  __shared__ char VtB2[2][16384];
  __shared__ unsigned short Pl[4][2][16][40];

  const int tid  = threadIdx.x;
  const int lane = tid & 63;
  const int wave = tid >> 6;
  const int qh   = wave >> 1;              // q half
  const int kh   = wave & 1;               // kv half
  const int h    = blockIdx.y;
  const int kvh  = h >> 2;
  const int pair = blockIdx.x;             // [0,16)
  const int lr   = lane & 15;
  const int g    = lane >> 4;
  const int lk8  = g * 8;
  const int blkl = h * 16 + pair;
  const int CVT_LIM = (HID * HID) / 4;
  int itg = 0;
  int pendidx = 0x7FFFFFFF;
  float4 pend;

  auto stageK = [&](int kv0, int buf) {
#pragma unroll
    for (int j = 0; j < 4; ++j) {
      const int row  = j * 16 + (tid >> 4);
      const int colb = ((tid & 15) << 4) ^ ((row & 15) << 4);
      const char* src =
          (const char*)(K + (size_t)(kv0 + row) * KVW + (size_t)kvh * HD) + colb;
      gld_lds16(src, &KlB[buf][row * 256 + ((tid & 15) << 4)]);
    }
  };
  auto stageV = [&](int kv0, int buf) {
#pragma unroll
    for (int j = 0; j < 4; ++j) {
      const int row  = j * 32 + (tid >> 3);
      const int colb = ((tid & 7) << 4) ^ ((row & 7) << 4);
      const char* src =
          (const char*)(VtG + ((size_t)kvh * HD + row) * S_LEN + kv0) + colb;
      gld_lds16(src, &VtB2[buf][row * 128 + ((tid & 7) << 4)]);
    }
  };
  // K frag: kv row = kh*32 + kf*16 + lr (row&15 == lr), d = c*32 + g*8 + j
  auto rdK = [&](int buf, int kf, int c) {
    const int row = kh * 32 + kf * 16 + lr;
    return *(const bf16x8_t*)&KlB[buf][row * 256 +
                                       ((c * 64 + g * 16) ^ (lr << 4))];
  };
  // V^T frag: d row = c*16 + lr, kv-local = kh*32 + g*8 + j
  auto rdV = [&](int buf, int c) {
    const int row = c * 16 + lr;
    return *(const bf16x8_t*)&VtB2[buf][row * 128 +
                                        ((kh * 64 + g * 16) ^ ((lr & 7) << 4))];
  };

  for (int pass = 0; pass < 2; ++pass) {
    const int qb = pass == 0 ? (31 - pair) : pair;
    const int q0 = qb * 64;
    const int nkv = qb + 1;

    // Q B-frags for 32 q rows (2 x 16-frag), q = q0 + qh*32 + qq*16 + lr
    bf16x8_t qf[2][4];
#pragma unroll
    for (int qq = 0; qq < 2; ++qq) {
      const unsigned short* qp =
          Q + (size_t)(q0 + qh * 32 + qq * 16 + lr) * HID + (size_t)h * HD;
#pragma unroll
      for (int c = 0; c < 4; ++c)
        qf[qq][c] = *(const bf16x8_t*)(const void*)(qp + c * 32 + lk8);
    }
    f32x4_t oacc[2][8];
#pragma unroll
    for (int qq = 0; qq < 2; ++qq)
#pragma unroll
      for (int c = 0; c < 8; ++c) oacc[qq][c] = f32x4_t{0.f, 0.f, 0.f, 0.f};
    float m_run[2] = {-1e30f, -1e30f};
    float l_run[2] = {0.f, 0.f};

    stageK(0, 0); stageV(0, 0);
    asm volatile("s_waitcnt vmcnt(0)" ::: "memory");
    __builtin_amdgcn_sched_barrier(0);
    __builtin_amdgcn_s_barrier();

    for (int it = 0; it < nkv; ++it) {
      const int kv0 = it * 64;
      const int buf = it & 1;

      // hidden Wo-cvt: flush previous, issue next load
      if (pendidx < CVT_LIM) {
        ushort4 o;
        o.x = f2b(pend.x); o.y = f2b(pend.y);
        o.z = f2b(pend.z); o.w = f2b(pend.w);
        reinterpret_cast<ushort4*>(WoB)[pendidx] = o;
      }
      pendidx = (blkl * 33 + itg) * 256 + tid;
      ++itg;
      if (pendidx < CVT_LIM)
        pend = reinterpret_cast<const float4*>(WoF)[pendidx];

      if (it + 1 < nkv) { stageK(kv0 + 64, buf ^ 1); stageV(kv0 + 64, buf ^ 1); }

      // ---- S^T partial = K[kh slice] * Q[qh slice] ----
      // col = q = q0+qh*32+qq*16+(lane&15); row = kv = kh*32+kf*16+g*4+r
      f32x4_t sacc[2][2];
#pragma unroll
      for (int qq = 0; qq < 2; ++qq)
#pragma unroll
        for (int kf = 0; kf < 2; ++kf) sacc[qq][kf] = f32x4_t{0.f, 0.f, 0.f, 0.f};
#pragma unroll
      for (int c = 0; c < 4; ++c) {
        bf16x8_t k0 = rdK(buf, 0, c), k1 = rdK(buf, 1, c);
#pragma unroll
        for (int qq = 0; qq < 2; ++qq) {
          sacc[qq][0] = __builtin_amdgcn_mfma_f32_16x16x32_bf16(k0, qf[qq][c], sacc[qq][0], 0, 0, 0);
          sacc[qq][1] = __builtin_amdgcn_mfma_f32_16x16x32_bf16(k1, qf[qq][c], sacc[qq][1], 0, 0, 0);
        }
      }

      // ---- partial softmax over this wave's 32 kv rows (exp2 domain) ----
      const bool diag = (it == nkv - 1);
      float p[2][8];
      float mloc[2] = {-3e38f, -3e38f};
#pragma unroll
      for (int qq = 0; qq < 2; ++qq) {
        const int qg = q0 + qh * 32 + qq * 16 + lr;
#pragma unroll
        for (int kf = 0; kf < 2; ++kf)
#pragma unroll
          for (int r = 0; r < 4; ++r) {
            float x = sacc[qq][kf][r];
            if (diag) {
              int kg = kv0 + kh * 32 + kf * 16 + g * 4 + r;
              if (kg > qg) x = -3e38f;
            }
            p[qq][kf * 4 + r] = x;
            mloc[qq] = fmaxf(mloc[qq], x);
          }
        mloc[qq] = fmaxf(mloc[qq], __shfl_xor(mloc[qq], 16));
        mloc[qq] = fmaxf(mloc[qq], __shfl_xor(mloc[qq], 32));
      }

      if (__any((mloc[0] > m_run[0] + 8.f) || (mloc[1] > m_run[1] + 8.f))) {
#pragma unroll
        for (int qq = 0; qq < 2; ++qq) {
          float m_new = fmaxf(m_run[qq], mloc[qq]);
          float alpha = fexp2(m_run[qq] - m_new);
          float a4[4];
#pragma unroll
          for (int r = 0; r < 4; ++r) a4[r] = __shfl(alpha, g * 4 + r);
#pragma unroll
          for (int c = 0; c < 8; ++c)
#pragma unroll
            for (int r = 0; r < 4; ++r) oacc[qq][c][r] *= a4[r];
          l_run[qq] *= alpha;
          m_run[qq] = m_new;
        }
      }

#pragma unroll
      for (int qq = 0; qq < 2; ++qq) {
        float ssum = 0.f;
#pragma unroll
        for (int i = 0; i < 8; ++i) {
          float e = fexp2(p[qq][i] - m_run[qq]);
          p[qq][i] = e;
          ssum += e;
        }
        ssum += __shfl_xor(ssum, 16);
        ssum += __shfl_xor(ssum, 32);
        l_run[qq] += ssum;
      }

      // ---- store P partial (q rows x 32 kv-local), wave-local ----
#pragma unroll
      for (int qq = 0; qq < 2; ++qq)
#pragma unroll
        for (int kf = 0; kf < 2; ++kf) {
          ushort4 w;
          w.x = f2b(p[qq][kf * 4 + 0]); w.y = f2b(p[qq][kf * 4 + 1]);
          w.z = f2b(p[qq][kf * 4 + 2]); w.w = f2b(p[qq][kf * 4 + 3]);
          *(ushort4*)(void*)&Pl[wave][qq][lr][kf * 16 + g * 4] = w;
        }

      // ---- PV partial: oacc[qq] += P[qq] * V[kh slice] ----
#pragma unroll
      for (int qq = 0; qq < 2; ++qq) {
        bf16x8_t pf = *(const bf16x8_t*)(const void*)&Pl[wave][qq][lr][g * 8];
#pragma unroll
        for (int c = 0; c < 8; ++c)
          oacc[qq][c] = __builtin_amdgcn_mfma_f32_16x16x32_bf16(pf, rdV(buf, c),
                                                               oacc[qq][c], 0, 0, 0);
      }

      if (it + 1 < nkv) { asm volatile("s_waitcnt vmcnt(0)" ::: "memory"); }
      __builtin_amdgcn_sched_barrier(0);
      __builtin_amdgcn_s_barrier();
    }

    // ---- cross-wave merge (kv-split pair shares q rows) ----
    // last tile barrier passed: all K/V LDS reads done -> KlB reusable
    if (kh == 1) {
      float* mlp = (float*)&VtB2[0][0] + (qh * 64 + lane) * 4;
      mlp[0] = m_run[0]; mlp[1] = l_run[0];
      mlp[2] = m_run[1]; mlp[3] = l_run[1];
      float* op = (float*)&KlB[0][0] + qh * 4096 + lane * 64;
#pragma unroll
      for (int qq = 0; qq < 2; ++qq)
#pragma unroll
        for (int c = 0; c < 8; ++c)
#pragma unroll
          for (int r = 0; r < 4; ++r)
            op[qq * 32 + c * 4 + r] = oacc[qq][c][r];
    }
    __builtin_amdgcn_s_barrier();
    if (kh == 0) {
      const float* mlp = (const float*)&VtB2[0][0] + (qh * 64 + lane) * 4;
      const float* op  = (const float*)&KlB[0][0] + qh * 4096 + lane * 64;
#pragma unroll
      for (int qq = 0; qq < 2; ++qq) {
        float m1 = mlp[qq * 2 + 0], l1 = mlp[qq * 2 + 1];
        float ms = fmaxf(m_run[qq], m1);
        float w0 = fexp2(m_run[qq] - ms), w1 = fexp2(m1 - ms);
        float linv = 1.f / (l_run[qq] * w0 + l1 * w1);
        float s0 = w0 * linv, s1 = w1 * linv;
        float s0r[4], s1r[4];
#pragma unroll
        for (int r = 0; r < 4; ++r) {
          s0r[r] = __shfl(s0, g * 4 + r);
          s1r[r] = __shfl(s1, g * 4 + r);
        }
#pragma unroll
        for (int r = 0; r < 4; ++r) {
          const int row = q0 + qh * 32 + qq * 16 + g * 4 + r;
#pragma unroll
          for (int c = 0; c < 8; ++c) {
            float o = oacc[qq][c][r] * s0r[r] + op[qq * 32 + c * 4 + r] * s1r[r];
            O[(size_t)row * HID + (size_t)h * HD + c * 16 + lr] = f2b(o);
          }
        }
      }
    }
    __builtin_amdgcn_s_barrier();  // protect merge regions from next-pass staging
  }

  // final pending cvt flush
  if (pendidx < CVT_LIM) {
    ushort4 o;
    o.x = f2b(pend.x); o.y = f2b(pend.y);
    o.z = f2b(pend.z); o.w = f2b(pend.w);
    reinterpret_cast<ushort4*>(WoB)[pendidx] = o;
  }
}

// ---------------- host launch ----------------
extern "C" void kernel_launch(void* const* d_in, const int* in_sizes, int n_in,
                              void* d_out, int out_size, void* d_ws, size_t ws_size,
                              hipStream_t stream) {
  (void)in_sizes; (void)n_in; (void)out_size; (void)ws_size;
  const float* X  = (const float*)d_in[0];
  const float* Wq = (const float*)d_in[1];
  const float* Wk = (const float*)d_in[2];
  const float* Wv = (const float*)d_in[3];
  const float* Wo = (const float*)d_in[4];
  const int*  pos = (const int*)d_in[5];
  float* out = (float*)d_out;

  unsigned short* Xb  = (unsigned short*)d_ws;
  unsigned short* Wqb = Xb  + (size_t)S_LEN * HID;
  unsigned short* Wkb = Wqb + (size_t)HID * HID;
  unsigned short* Wvb = Wkb + (size_t)KVW * HID;
  unsigned short* Wob = Wvb + (size_t)KVW * HID;
  unsigned short* Qb  = Wob + (size_t)HID * HID;
  unsigned short* Kb  = Qb  + (size_t)S_LEN * HID;
  unsigned short* VtB = Kb  + (size_t)S_LEN * KVW;
  unsigned short* AOb = VtB + (size_t)S_LEN * KVW;

  cvt4_kernel<<<2048, 256, 0, stream>>>(X, Wq, Wk, Wv, Xb);

  gemm4p_kernel<192, 2><<<dim3(QKVN / 192, S_LEN / 128), 512, 0, stream>>>(
      Xb, Wqb, Qb, Kb, VtB, QKVN, HID);

  rope_kernel<<<2048, 256, 0, stream>>>(Qb, Kb, pos);

  attn_kernel<<<dim3(16, NH), 256, 0, stream>>>(Qb, Kb, VtB, AOb, Wo, Wob);

  gemm4w_kernel<128, 1><<<dim3(HID / 128, S_LEN / 128), 256, 0, stream>>>(
      AOb, Wob, out, nullptr, nullptr, HID, HID);
}

// Round 17
// 276.056 us; speedup vs baseline: 1.2207x; 1.2207x over previous
//
#include <hip/hip_runtime.h>
#include <hip/hip_bf16.h>
#include <cstdint>
#include <cstddef>

#define S_LEN 2048
#define HID   4096
#define HD    128
#define NH    32
#define NKV   8
#define KVW   (NKV * HD)        /* 1024 */
#define QKVN  (HID + 2 * KVW)   /* 6144 */

typedef __bf16 bf16x8_t __attribute__((ext_vector_type(8)));
typedef float  f32x4_t  __attribute__((ext_vector_type(4)));
typedef unsigned short u16x8_t __attribute__((ext_vector_type(8)));

__device__ __forceinline__ unsigned short f2b(float f) {
  unsigned u = __float_as_uint(f);
  u += 0x7FFFu + ((u >> 16) & 1u);
  return (unsigned short)(u >> 16);
}
__device__ __forceinline__ float b2f(unsigned short v) {
  return __uint_as_float(((unsigned)v) << 16);
}
// raw v_exp_f32: D = 2^S0 (fast HW transcendental; precise exp2f is ~20 inst)
__device__ __forceinline__ float fexp2(float x) {
  float r;
  asm("v_exp_f32 %0, %1" : "=v"(r) : "v"(x));
  return r;
}
__device__ __forceinline__ void gld_lds16(const void* g, void* l) {
  __builtin_amdgcn_global_load_lds(
      (const __attribute__((address_space(1))) void*)g,
      (__attribute__((address_space(3))) void*)l, 16, 0, 0);
}

// ---------- fused fp32 -> bf16 conversion: X | Wq | Wk | Wv in ONE launch ----------
__global__ void cvt4_kernel(const float* __restrict__ s0, const float* __restrict__ s1,
                            const float* __restrict__ s2, const float* __restrict__ s3,
                            unsigned short* __restrict__ dst) {
  const int B0 = 2097152;              // X      f4 count
  const int B1 = B0 + 4194304;         // + Wq
  const int B2 = B1 + 1048576;         // + Wk
  const int B3 = B2 + 1048576;         // + Wv
  int i = blockIdx.x * blockDim.x + threadIdx.x;
  int stride = gridDim.x * blockDim.x;
  for (; i < B3; i += stride) {
    const float* s; int off;
    if (i < B0)      { s = s0; off = i; }
    else if (i < B1) { s = s1; off = i - B0; }
    else if (i < B2) { s = s2; off = i - B1; }
    else             { s = s3; off = i - B2; }
    float4 v = reinterpret_cast<const float4*>(s)[off];
    ushort4 o;
    o.x = f2b(v.x); o.y = f2b(v.y); o.z = f2b(v.z); o.w = f2b(v.w);
    reinterpret_cast<ushort4*>(dst)[i] = o;
  }
}

// ---------------- RoPE (in-place on bf16 Q and K) ----------------
#define QSCALE 0.12751744846f   /* 1/sqrt(128) * log2(e) */
__global__ void rope_kernel(unsigned short* __restrict__ Q,
                            unsigned short* __restrict__ Kb,
                            const int* __restrict__ pos_ids) {
  const int total = S_LEN * (NH + NKV) * 64;
  int idx = blockIdx.x * blockDim.x + threadIdx.x;
  int stride = gridDim.x * blockDim.x;
  for (; idx < total; idx += stride) {
    int s   = idx / ((NH + NKV) * 64);
    int rem = idx % ((NH + NKV) * 64);
    int hp  = rem >> 6;
    int i   = rem & 63;
    unsigned short* ptr; int W, h;
    if (hp < NH) { ptr = Q;  W = HID; h = hp; }
    else         { ptr = Kb; W = KVW; h = hp - NH; }
    float pos = (float)pos_ids[s];
    float ang = pos * __expf(-(float)i * 0.14391156516f);
    float sn, cs;
    sincosf(ang, &sn, &cs);
    size_t base = (size_t)s * W + (size_t)h * HD + i;
    float lo = b2f(ptr[base]);
    float hi = b2f(ptr[base + 64]);
    float o0 = lo * cs - hi * sn;
    float o1 = hi * cs + lo * sn;
    if (hp < NH) { o0 *= QSCALE; o1 *= QSCALE; }
    ptr[base]      = f2b(o0);
    ptr[base + 64] = f2b(o1);
  }
}

// ------------- 8-wave 4-phase pipelined GEMM, 2 blocks/CU (r12, proven) -------------
template <int BN, int MODE>
__global__ __launch_bounds__(512, 4) void gemm4p_kernel(
    const unsigned short* __restrict__ A, const unsigned short* __restrict__ B,
    void* __restrict__ C0, void* __restrict__ C1, void* __restrict__ C2,
    int N, int K) {
  constexpr int NFR = BN / 64;
  constexpr int ABYTES = 128 * 128;
  constexpr int TILE_LDS = ABYTES + BN * 128;
  __shared__ char ldsB[2 * TILE_LDS];

  const int tid  = threadIdx.x;
  const int lane = tid & 63;
  const int wid  = tid >> 6;
  const int wm = wid >> 2, wn = wid & 3;
  const int lr = lane & 15, g = lane >> 4;
  const int bm = blockIdx.y * 128;
  const int bn = blockIdx.x * BN;
  const int nk = K >> 6;
  const int ni = nk >> 1;
  const int xr = (lr & 7) << 4;

  auto stage_u = [&](int t, int u) {
    if (t >= nk) return;
    const int riu = tid >> 3;
    const int cbs = ((tid & 7) << 4) ^ ((riu & 7) << 4);
    const char* src;
    if (u < 2)
      src = (const char*)A + ((size_t)(bm + u * 64 + riu) * K + t * 64) * 2 + cbs;
    else
      src = (const char*)B + ((size_t)(bn + (u - 2) * 64 + riu) * K + t * 64) * 2 + cbs;
    gld_lds16(src, ldsB + (t & 1) * TILE_LDS + u * 8192 + tid * 16);
  };

  auto rdA = [&](const char* bb, int m, int k) {
    const int row = wm * 64 + m * 16 + lr;
    return *(const bf16x8_t*)(bb + row * 128 + ((k * 64 + g * 16) ^ xr));
  };
  auto rdB = [&](const char* bb, int n, int k) {
    const int row = wn * (BN / 4) + n * 16 + lr;
    return *(const bf16x8_t*)(bb + ABYTES + row * 128 + ((k * 64 + g * 16) ^ xr));
  };

  for (int t = 0; t < 2; ++t)
    for (int u = 0; u < 2 + NFR; ++u) stage_u(t, u);
  asm volatile("s_waitcnt vmcnt(0)" ::: "memory");
  __builtin_amdgcn_sched_barrier(0);
  __builtin_amdgcn_s_barrier();

  f32x4_t acc[4][NFR];
#pragma unroll
  for (int m = 0; m < 4; ++m)
#pragma unroll
    for (int n = 0; n < NFR; ++n) acc[m][n] = f32x4_t{0.f, 0.f, 0.f, 0.f};

  bf16x8_t bfr[NFR][2], af[2][2];

#define MFMA_BLOCK(MB)                                                        \
  __builtin_amdgcn_s_setprio(1);                                              \
  _Pragma("unroll") for (int m = 0; m < 2; ++m)                               \
    _Pragma("unroll") for (int n = 0; n < NFR; ++n)                           \
      _Pragma("unroll") for (int k = 0; k < 2; ++k)                           \
        acc[(MB) + m][n] = __builtin_amdgcn_mfma_f32_16x16x32_bf16(           \
            af[m][k], bfr[n][k], acc[(MB) + m][n], 0, 0, 0);                  \
  __builtin_amdgcn_s_setprio(0);

#define GATE()                                                                \
  __builtin_amdgcn_s_barrier();                                               \
  asm volatile("s_waitcnt lgkmcnt(0)" ::: "memory");                          \
  __builtin_amdgcn_sched_barrier(0);

#define RD_A2(bb, m0)                                                         \
  _Pragma("unroll") for (int m = 0; m < 2; ++m)                               \
    _Pragma("unroll") for (int k = 0; k < 2; ++k)                             \
      af[m][k] = rdA(bb, (m0) + m, k);

#define RD_B(bb)                                                              \
  _Pragma("unroll") for (int n = 0; n < NFR; ++n)                             \
    _Pragma("unroll") for (int k = 0; k < 2; ++k)                             \
      bfr[n][k] = rdB(bb, n, k);

  for (int i = 0; i < ni; ++i) {
    const char* bE = ldsB;
    const char* bO = ldsB + TILE_LDS;
    const int tO = 2 * i + 1, tE2 = 2 * i + 2, tO2 = 2 * i + 3;
    const bool last = (i == ni - 1);

    RD_B(bE);
    RD_A2(bE, 0);
    if (i > 0) { stage_u(tO, 0); stage_u(tO, 1); }
    GATE(); MFMA_BLOCK(0);
    __builtin_amdgcn_s_barrier();

    RD_A2(bE, 2);
#pragma unroll
    for (int u = 0; u < NFR; ++u) stage_u(tE2, 2 + u);
    GATE(); MFMA_BLOCK(2);
    if (last) { asm volatile("s_waitcnt vmcnt(0)" ::: "memory"); }
    else      { asm volatile("s_waitcnt vmcnt(%0)" :: "n"(NFR) : "memory"); }
    __builtin_amdgcn_sched_barrier(0);
    __builtin_amdgcn_s_barrier();

    RD_B(bO);
    RD_A2(bO, 0);
    stage_u(tE2, 0); stage_u(tE2, 1);
    GATE(); MFMA_BLOCK(0);
    __builtin_amdgcn_s_barrier();

    RD_A2(bO, 2);
#pragma unroll
    for (int u = 0; u < NFR; ++u) stage_u(tO2, 2 + u);
    GATE(); MFMA_BLOCK(2);
    if (!last) { asm volatile("s_waitcnt vmcnt(%0)" :: "n"(NFR) : "memory"); }
    __builtin_amdgcn_sched_barrier(0);
    __builtin_amdgcn_s_barrier();
  }
#undef MFMA_BLOCK
#undef GATE
#undef RD_A2
#undef RD_B

#pragma unroll
  for (int mf = 0; mf < 4; ++mf) {
    const int row0 = bm + wm * 64 + mf * 16 + g * 4;
#pragma unroll
    for (int nf = 0; nf < NFR; ++nf) {
      const int col = bn + wn * (BN / 4) + nf * 16 + lr;
      if constexpr (MODE == 1) {
#pragma unroll
        for (int r = 0; r < 4; ++r)
          ((float*)C0)[(size_t)(row0 + r) * N + col] = acc[mf][nf][r];
      } else {
        if (col < HID) {
#pragma unroll
          for (int r = 0; r < 4; ++r)
            ((unsigned short*)C0)[(size_t)(row0 + r) * HID + col] = f2b(acc[mf][nf][r]);
        } else if (col < HID + KVW) {
#pragma unroll
          for (int r = 0; r < 4; ++r)
            ((unsigned short*)C1)[(size_t)(row0 + r) * KVW + (col - HID)] = f2b(acc[mf][nf][r]);
        } else {
          const int c2 = col - HID - KVW;
          ushort4 w;
          w.x = f2b(acc[mf][nf][0]); w.y = f2b(acc[mf][nf][1]);
          w.z = f2b(acc[mf][nf][2]); w.w = f2b(acc[mf][nf][3]);
          *(ushort4*)(void*)&((unsigned short*)C2)[(size_t)c2 * S_LEN + row0] = w;
        }
      }
    }
  }
}

// ---- 4-wave 4-phase pipelined GEMM (r13) — short out-proj ----
template <int BN, int MODE>
__global__ __launch_bounds__(256, 2) void gemm4w_kernel(
    const unsigned short* __restrict__ A, const unsigned short* __restrict__ B,
    void* __restrict__ C0, void* __restrict__ C1, void* __restrict__ C2,
    int N, int K) {
  constexpr int NFRW = BN / 32;
  constexpr int ABYTES = 128 * 128;
  constexpr int TILE_LDS = ABYTES + BN * 128;
  __shared__ char ldsB[2 * TILE_LDS];

  const int tid  = threadIdx.x;
  const int lane = tid & 63;
  const int wid  = tid >> 6;
  const int wm = wid >> 1, wn = wid & 1;
  const int lr = lane & 15, g = lane >> 4;
  const int bm = blockIdx.y * 128;
  const int bn = blockIdx.x * BN;
  const int nk = K >> 6;
  const int ni = nk >> 1;
  const int xr = (lr & 7) << 4;

  auto stage_u = [&](int t, int u) {
    if (t >= nk) return;
    const int riu = tid >> 3;
    const int cbs = ((tid & 7) << 4) ^ ((riu & 7) << 4);
    const char* src;
    if (u < 4)
      src = (const char*)A + ((size_t)(bm + u * 32 + riu) * K + t * 64) * 2 + cbs;
    else
      src = (const char*)B + ((size_t)(bn + (u - 4) * 32 + riu) * K + t * 64) * 2 + cbs;
    gld_lds16(src, ldsB + (t & 1) * TILE_LDS + u * 4096 + tid * 16);
  };

  auto rdA = [&](const char* bb, int m, int k) {
    const int row = wm * 64 + m * 16 + lr;
    return *(const bf16x8_t*)(bb + row * 128 + ((k * 64 + g * 16) ^ xr));
  };
  auto rdB = [&](const char* bb, int n, int k) {
    const int row = wn * (BN / 2) + n * 16 + lr;
    return *(const bf16x8_t*)(bb + ABYTES + row * 128 + ((k * 64 + g * 16) ^ xr));
  };

  for (int t = 0; t < 2; ++t)
    for (int u = 0; u < 4 + NFRW; ++u) stage_u(t, u);
  asm volatile("s_waitcnt vmcnt(0)" ::: "memory");
  __builtin_amdgcn_sched_barrier(0);
  __builtin_amdgcn_s_barrier();

  f32x4_t acc[4][NFRW];
#pragma unroll
  for (int m = 0; m < 4; ++m)
#pragma unroll
    for (int n = 0; n < NFRW; ++n) acc[m][n] = f32x4_t{0.f, 0.f, 0.f, 0.f};

  bf16x8_t bfr[NFRW][2], af[2][2];

#define MFMA_BLOCK(MB)                                                        \
  __builtin_amdgcn_s_setprio(1);                                              \
  _Pragma("unroll") for (int m = 0; m < 2; ++m)                               \
    _Pragma("unroll") for (int n = 0; n < NFRW; ++n)                          \
      _Pragma("unroll") for (int k = 0; k < 2; ++k)                           \
        acc[(MB) + m][n] = __builtin_amdgcn_mfma_f32_16x16x32_bf16(           \
            af[m][k], bfr[n][k], acc[(MB) + m][n], 0, 0, 0);                  \
  __builtin_amdgcn_s_setprio(0);

#define GATE()                                                                \
  __builtin_amdgcn_s_barrier();                                               \
  asm volatile("s_waitcnt lgkmcnt(0)" ::: "memory");                          \
  __builtin_amdgcn_sched_barrier(0);

#define RD_A2(bb, m0)                                                         \
  _Pragma("unroll") for (int m = 0; m < 2; ++m)                               \
    _Pragma("unroll") for (int k = 0; k < 2; ++k)                             \
      af[m][k] = rdA(bb, (m0) + m, k);

#define RD_B(bb)                                                              \
  _Pragma("unroll") for (int n = 0; n < NFRW; ++n)                            \
    _Pragma("unroll") for (int k = 0; k < 2; ++k)                             \
      bfr[n][k] = rdB(bb, n, k);

  for (int i = 0; i < ni; ++i) {
    const char* bE = ldsB;
    const char* bO = ldsB + TILE_LDS;
    const int tO = 2 * i + 1, tE2 = 2 * i + 2, tO2 = 2 * i + 3;
    const bool last = (i == ni - 1);

    RD_B(bE);
    RD_A2(bE, 0);
    if (i > 0) {
#pragma unroll
      for (int u = 0; u < 4; ++u) stage_u(tO, u);
    }
    GATE(); MFMA_BLOCK(0);
    __builtin_amdgcn_s_barrier();

    RD_A2(bE, 2);
#pragma unroll
    for (int u = 0; u < NFRW; ++u) stage_u(tE2, 4 + u);
    GATE(); MFMA_BLOCK(2);
    if (last) { asm volatile("s_waitcnt vmcnt(0)" ::: "memory"); }
    else      { asm volatile("s_waitcnt vmcnt(%0)" :: "n"(NFRW) : "memory"); }
    __builtin_amdgcn_sched_barrier(0);
    __builtin_amdgcn_s_barrier();

    RD_B(bO);
    RD_A2(bO, 0);
#pragma unroll
    for (int u = 0; u < 4; ++u) stage_u(tE2, u);
    GATE(); MFMA_BLOCK(0);
    __builtin_amdgcn_s_barrier();

    RD_A2(bO, 2);
#pragma unroll
    for (int u = 0; u < NFRW; ++u) stage_u(tO2, 4 + u);
    GATE(); MFMA_BLOCK(2);
    if (!last) { asm volatile("s_waitcnt vmcnt(%0)" :: "n"(NFRW) : "memory"); }
    __builtin_amdgcn_sched_barrier(0);
    __builtin_amdgcn_s_barrier();
  }
#undef MFMA_BLOCK
#undef GATE
#undef RD_A2
#undef RD_B

#pragma unroll
  for (int mf = 0; mf < 4; ++mf) {
    const int row0 = bm + wm * 64 + mf * 16 + g * 4;
#pragma unroll
    for (int nf = 0; nf < NFRW; ++nf) {
      const int col = bn + wn * (BN / 2) + nf * 16 + lr;
      if constexpr (MODE == 1) {
#pragma unroll
        for (int r = 0; r < 4; ++r)
          ((float*)C0)[(size_t)(row0 + r) * N + col] = acc[mf][nf][r];
      } else {
        if (col < HID) {
#pragma unroll
          for (int r = 0; r < 4; ++r)
            ((unsigned short*)C0)[(size_t)(row0 + r) * HID + col] = f2b(acc[mf][nf][r]);
        } else if (col < HID + KVW) {
#pragma unroll
          for (int r = 0; r < 4; ++r)
            ((unsigned short*)C1)[(size_t)(row0 + r) * KVW + (col - HID)] = f2b(acc[mf][nf][r]);
        } else {
          const int c2 = col - HID - KVW;
          ushort4 w;
          w.x = f2b(acc[mf][nf][0]); w.y = f2b(acc[mf][nf][1]);
          w.z = f2b(acc[mf][nf][2]); w.w = f2b(acc[mf][nf][3]);
          *(ushort4*)(void*)&((unsigned short*)C2)[(size_t)c2 * S_LEN + row0] = w;
        }
      }
    }
  }
}

// ---------------- flash attention v5 + hidden Wo-cvt (r15, best: 101.6us) ----------------
__global__ __launch_bounds__(256) void attn_kernel(
    const unsigned short* __restrict__ Q, const unsigned short* __restrict__ K,
    const unsigned short* __restrict__ VtG, unsigned short* __restrict__ O,
    const float* __restrict__ WoF, unsigned short* __restrict__ WoB) {
  __shared__ char KlB[2][16384];
  __shared__ char VtB2[2][16384];
  __shared__ unsigned short Pl[4][16][72];

  const int tid  = threadIdx.x;
  const int lane = tid & 63;
  const int wave = tid >> 6;
  const int h    = blockIdx.y;
  const int kvh  = h >> 2;
  const int pair = blockIdx.x;             // [0,16)
  const int lr   = lane & 15;
  const int g    = lane >> 4;
  const int lk8  = g * 8;
  const int blkl = h * 16 + pair;            // [0,512)
  const int CVT_LIM = (HID * HID) / 4;       // float4 count of Wo
  int itg = 0;
  int pendidx = 0x7FFFFFFF;
  float4 pend;

  auto stageK = [&](int kv0, int buf) {
#pragma unroll
    for (int j = 0; j < 4; ++j) {
      const int row  = j * 16 + (tid >> 4);
      const int colb = ((tid & 15) << 4) ^ ((row & 15) << 4);
      const char* src =
          (const char*)(K + (size_t)(kv0 + row) * KVW + (size_t)kvh * HD) + colb;
      gld_lds16(src, &KlB[buf][row * 256 + ((tid & 15) << 4)]);
    }
  };
  auto stageV = [&](int kv0, int buf) {
#pragma unroll
    for (int j = 0; j < 4; ++j) {
      const int row  = j * 32 + (tid >> 3);
      const int colb = ((tid & 7) << 4) ^ ((row & 7) << 4);
      const char* src =
          (const char*)(VtG + ((size_t)kvh * HD + row) * S_LEN + kv0) + colb;
      gld_lds16(src, &VtB2[buf][row * 128 + ((tid & 7) << 4)]);
    }
  };
  auto rdK = [&](int buf, int n, int c) {
    const int row = n * 16 + lr;
    return *(const bf16x8_t*)&KlB[buf][row * 256 +
                                       ((c * 64 + g * 16) ^ ((lr & 15) << 4))];
  };
  auto rdV = [&](int buf, int c, int half) {
    const int row = c * 16 + lr;
    return *(const bf16x8_t*)&VtB2[buf][row * 128 +
                                        ((half * 64 + g * 16) ^ ((lr & 7) << 4))];
  };

  for (int pass = 0; pass < 2; ++pass) {
    const int qb = pass == 0 ? (31 - pair) : pair;
    const int q0 = qb * 64;
    const int qrow = q0 + wave * 16;
    const int nkv = qb + 1;

    bf16x8_t qf[4];
    {
      const unsigned short* qp = Q + (size_t)(qrow + lr) * HID + (size_t)h * HD;
#pragma unroll
      for (int c = 0; c < 4; ++c)
        qf[c] = *(const bf16x8_t*)(const void*)(qp + c * 32 + lk8);
    }
    f32x4_t oacc[8];
#pragma unroll
    for (int c = 0; c < 8; ++c) oacc[c] = f32x4_t{0.f, 0.f, 0.f, 0.f};
    float m_run = -3e38f, l_run = 0.f;

    stageK(0, 0); stageV(0, 0);
    asm volatile("s_waitcnt vmcnt(0)" ::: "memory");
    __builtin_amdgcn_sched_barrier(0);
    __builtin_amdgcn_s_barrier();

    for (int it = 0; it < nkv; ++it) {
      const int kv0 = it * 64;
      const int buf = it & 1;

      // ---- hidden Wo-cvt: flush previous, issue next load ----
      if (pendidx < CVT_LIM) {
        ushort4 o;
        o.x = f2b(pend.x); o.y = f2b(pend.y);
        o.z = f2b(pend.z); o.w = f2b(pend.w);
        reinterpret_cast<ushort4*>(WoB)[pendidx] = o;
      }
      pendidx = (blkl * 33 + itg) * 256 + tid;
      ++itg;
      if (pendidx < CVT_LIM)
        pend = reinterpret_cast<const float4*>(WoF)[pendidx];

      if (it + 1 < nkv) { stageK(kv0 + 64, buf ^ 1); stageV(kv0 + 64, buf ^ 1); }

      // ---- S^T = K * Q^T (Q pre-scaled: sacc already in log2 units) ----
      f32x4_t sacc[4];
#pragma unroll
      for (int n = 0; n < 4; ++n) sacc[n] = f32x4_t{0.f, 0.f, 0.f, 0.f};
#pragma unroll
      for (int c = 0; c < 4; ++c) {
        bf16x8_t qc = qf[c];
#pragma unroll
        for (int n = 0; n < 4; ++n)
          sacc[n] = __builtin_amdgcn_mfma_f32_16x16x32_bf16(rdK(buf, n, c), qc,
                                                            sacc[n], 0, 0, 0);
      }

      // ---- softmax over k (exp2 domain, raw v_exp_f32) ----
      const int qg = qrow + lr;
      const bool diag = (it == nkv - 1);
      float p[16];
      float mloc = -3e38f;
#pragma unroll
      for (int n = 0; n < 4; ++n)
#pragma unroll
        for (int r = 0; r < 4; ++r) {
          float x = sacc[n][r];
          if (diag) {
            int kg = kv0 + n * 16 + g * 4 + r;
            if (kg > qg) x = -3e38f;
          }
          p[n * 4 + r] = x;
          mloc = fmaxf(mloc, x);
        }
      mloc = fmaxf(mloc, __shfl_xor(mloc, 16));
      mloc = fmaxf(mloc, __shfl_xor(mloc, 32));

      if (__any(mloc > m_run + 8.f)) {
        float m_new = fmaxf(m_run, mloc);
        float alpha = fexp2(m_run - m_new);
        float a4[4];
#pragma unroll
        for (int r = 0; r < 4; ++r) a4[r] = __shfl(alpha, g * 4 + r);
#pragma unroll
        for (int c = 0; c < 8; ++c)
#pragma unroll
          for (int r = 0; r < 4; ++r) oacc[c][r] *= a4[r];
        l_run *= alpha;
        m_run = m_new;
      }

      float ssum = 0.f;
#pragma unroll
      for (int i = 0; i < 16; ++i) {
        float e = fexp2(p[i] - m_run);
        p[i] = e;
        ssum += e;
      }
      ssum += __shfl_xor(ssum, 16);
      ssum += __shfl_xor(ssum, 32);
      l_run += ssum;

#pragma unroll
      for (int n = 0; n < 4; ++n) {
        ushort4 w;
        w.x = f2b(p[n * 4 + 0]); w.y = f2b(p[n * 4 + 1]);
        w.z = f2b(p[n * 4 + 2]); w.w = f2b(p[n * 4 + 3]);
        *(ushort4*)(void*)&Pl[wave][lr][n * 16 + g * 4] = w;
      }

      // ---- PV ----
#pragma unroll
      for (int half = 0; half < 2; ++half) {
        bf16x8_t pf = *(const bf16x8_t*)(const void*)&Pl[wave][lr][half * 32 + lk8];
#pragma unroll
        for (int c = 0; c < 8; ++c)
          oacc[c] = __builtin_amdgcn_mfma_f32_16x16x32_bf16(pf, rdV(buf, c, half),
                                                            oacc[c], 0, 0, 0);
      }

      if (it + 1 < nkv) { asm volatile("s_waitcnt vmcnt(0)" ::: "memory"); }
      __builtin_amdgcn_sched_barrier(0);
      __builtin_amdgcn_s_barrier();
    }

    float linv[4];
#pragma unroll
    for (int r = 0; r < 4; ++r) linv[r] = 1.f / __shfl(l_run, g * 4 + r);
#pragma unroll
    for (int r = 0; r < 4; ++r) {
      int row = qrow + g * 4 + r;
#pragma unroll
      for (int c = 0; c < 8; ++c)
        O[(size_t)row * HID + (size_t)h * HD + c * 16 + lr] = f2b(oacc[c][r] * linv[r]);
    }
  }

  // final pending cvt flush
  if (pendidx < CVT_LIM) {
    ushort4 o;
    o.x = f2b(pend.x); o.y = f2b(pend.y);
    o.z = f2b(pend.z); o.w = f2b(pend.w);
    reinterpret_cast<ushort4*>(WoB)[pendidx] = o;
  }
}

// ---------------- host launch ----------------
extern "C" void kernel_launch(void* const* d_in, const int* in_sizes, int n_in,
                              void* d_out, int out_size, void* d_ws, size_t ws_size,
                              hipStream_t stream) {
  (void)in_sizes; (void)n_in; (void)out_size; (void)ws_size;
  const float* X  = (const float*)d_in[0];
  const float* Wq = (const float*)d_in[1];
  const float* Wk = (const float*)d_in[2];
  const float* Wv = (const float*)d_in[3];
  const float* Wo = (const float*)d_in[4];
  const int*  pos = (const int*)d_in[5];
  float* out = (float*)d_out;

  unsigned short* Xb  = (unsigned short*)d_ws;
  unsigned short* Wqb = Xb  + (size_t)S_LEN * HID;
  unsigned short* Wkb = Wqb + (size_t)HID * HID;
  unsigned short* Wvb = Wkb + (size_t)KVW * HID;
  unsigned short* Wob = Wvb + (size_t)KVW * HID;
  unsigned short* Qb  = Wob + (size_t)HID * HID;
  unsigned short* Kb  = Qb  + (size_t)S_LEN * HID;
  unsigned short* VtB = Kb  + (size_t)S_LEN * KVW;
  unsigned short* AOb = VtB + (size_t)S_LEN * KVW;

  cvt4_kernel<<<2048, 256, 0, stream>>>(X, Wq, Wk, Wv, Xb);

  gemm4p_kernel<192, 2><<<dim3(QKVN / 192, S_LEN / 128), 512, 0, stream>>>(
      Xb, Wqb, Qb, Kb, VtB, QKVN, HID);

  rope_kernel<<<2048, 256, 0, stream>>>(Qb, Kb, pos);

  attn_kernel<<<dim3(16, NH), 256, 0, stream>>>(Qb, Kb, VtB, AOb, Wo, Wob);

  gemm4w_kernel<128, 1><<<dim3(HID / 128, S_LEN / 128), 256, 0, stream>>>(
      AOb, Wob, out, nullptr, nullptr, HID, HID);
}